// Round 2
// baseline (273.660 us; speedup 1.0000x reference)
//
#include <hip/hip_runtime.h>

typedef __attribute__((ext_vector_type(8))) short s16x8;   // 8 bf16
typedef __attribute__((ext_vector_type(4))) float f32x4;

#define HID 512
#define NROWS 8192
#define TAU_INV 1.25f

__device__ __forceinline__ float bf2f(short s) {
    union { unsigned u; float f; } v;
    v.u = ((unsigned)(unsigned short)s) << 16;
    return v.f;
}
__device__ __forceinline__ short f2bf(float f) {
    unsigned u = __float_as_uint(f);
    u += 0x7fffu + ((u >> 16) & 1u);   // round-to-nearest-even
    return (short)(u >> 16);
}

__device__ __forceinline__ void gload_lds16(const void* g, void* l) {
    __builtin_amdgcn_global_load_lds(
        (const __attribute__((address_space(1))) unsigned int*)g,
        (__attribute__((address_space(3))) unsigned int*)l, 16, 0, 0);
}

// fp32 -> bf16, 4 elems/thread
__global__ void convert_f32_bf16(const float* __restrict__ src, short* __restrict__ dst, int n)
{
    int i = (blockIdx.x * blockDim.x + threadIdx.x) * 4;
    if (i >= n) return;
    float4 v = *(const float4*)(src + i);
    short4 o;
    o.x = f2bf(v.x); o.y = f2bf(v.y); o.z = f2bf(v.z); o.w = f2bf(v.w);
    *(short4*)(dst + i) = o;
}

// ---------------------------------------------------------------------------
// NT GEMM: C[i,j] = act( sum_k A[i,k]*B[j,k] + bias[j] ), bf16 in/out, f32 acc
// M=8192 (grid.x*128), N=512 (grid.y*128), K=512. grid.z selects (A0,C0)/(A1,C1).
// 128x128 block tile, 4 waves of 64x64 (4x4 x mfma_f32_16x16x32_bf16).
// ---------------------------------------------------------------------------
__global__ __launch_bounds__(256, 2)
void gemm_proj(const short* __restrict__ A0, const short* __restrict__ A1,
               const short* __restrict__ B, const float* __restrict__ bias,
               short* __restrict__ C0, short* __restrict__ C1, int do_elu)
{
    __shared__ short ldsA[128 * 32];
    __shared__ short ldsB[128 * 32];
    const short* A = blockIdx.z ? A1 : A0;
    short* C = blockIdx.z ? C1 : C0;
    const int tid = threadIdx.x;
    const int w = tid >> 6, lane = tid & 63;
    const int wm = w >> 1, wn = w & 1;
    const int quad = lane >> 4, r16 = lane & 15;
    const int bM = blockIdx.x * 128, bN = blockIdx.y * 128;
    const int lrow = lane >> 2, lcol = (lane & 3) * 8;

    f32x4 acc[4][4] = {};

    for (int k0 = 0; k0 < HID; k0 += 32) {
        __syncthreads();
#pragma unroll
        for (int i = 0; i < 2; ++i) {
            int r0 = (w * 2 + i) * 16;
            gload_lds16(A + (size_t)(bM + r0 + lrow) * HID + k0 + lcol, &ldsA[r0 * 32]);
            gload_lds16(B + (size_t)(bN + r0 + lrow) * HID + k0 + lcol, &ldsB[r0 * 32]);
        }
        __syncthreads();
        s16x8 af[4], bfr[4];
#pragma unroll
        for (int t = 0; t < 4; ++t) {
            af[t]  = *(const s16x8*)&ldsA[(wm * 64 + t * 16 + r16) * 32 + quad * 8];
            bfr[t] = *(const s16x8*)&ldsB[(wn * 64 + t * 16 + r16) * 32 + quad * 8];
        }
#pragma unroll
        for (int tm = 0; tm < 4; ++tm)
#pragma unroll
            for (int tn = 0; tn < 4; ++tn)
                acc[tm][tn] = __builtin_amdgcn_mfma_f32_16x16x32_bf16(
                    af[tm], bfr[tn], acc[tm][tn], 0, 0, 0);
    }

#pragma unroll
    for (int tn = 0; tn < 4; ++tn) {
        int gcol = bN + wn * 64 + tn * 16 + r16;
        float bv = bias[gcol];
#pragma unroll
        for (int tm = 0; tm < 4; ++tm) {
#pragma unroll
            for (int r = 0; r < 4; ++r) {
                int grow = bM + wm * 64 + tm * 16 + quad * 4 + r;  // C/D: row=(lane>>4)*4+reg
                float v = acc[tm][tn][r] + bv;
                if (do_elu) v = v > 0.f ? v : __expf(v) - 1.f;
                C[(size_t)grow * HID + gcol] = f2bf(v);
            }
        }
    }
}

// ---------------------------------------------------------------------------
// Similarity kernel: per 128x128 tile, e = exp(dot(n1_i, n2_j)/tau); atomically
// accumulate rowsum[i] (+= sum_j e) and colsum[j] (+= sum_i e). S not stored.
// ---------------------------------------------------------------------------
__global__ __launch_bounds__(256, 2)
void gemm_sim(const short* __restrict__ N1, const short* __restrict__ N2,
              float* __restrict__ rowsum, float* __restrict__ colsum)
{
    __shared__ short ldsA[128 * 32];
    __shared__ short ldsB[128 * 32];
    const int tid = threadIdx.x;
    const int w = tid >> 6, lane = tid & 63;
    const int wm = w >> 1, wn = w & 1;
    const int quad = lane >> 4, r16 = lane & 15;
    const int bM = blockIdx.x * 128, bN = blockIdx.y * 128;
    const int lrow = lane >> 2, lcol = (lane & 3) * 8;

    f32x4 acc[4][4] = {};

    for (int k0 = 0; k0 < HID; k0 += 32) {
        __syncthreads();
#pragma unroll
        for (int i = 0; i < 2; ++i) {
            int r0 = (w * 2 + i) * 16;
            gload_lds16(N1 + (size_t)(bM + r0 + lrow) * HID + k0 + lcol, &ldsA[r0 * 32]);
            gload_lds16(N2 + (size_t)(bN + r0 + lrow) * HID + k0 + lcol, &ldsB[r0 * 32]);
        }
        __syncthreads();
        s16x8 af[4], bfr[4];
#pragma unroll
        for (int t = 0; t < 4; ++t) {
            af[t]  = *(const s16x8*)&ldsA[(wm * 64 + t * 16 + r16) * 32 + quad * 8];
            bfr[t] = *(const s16x8*)&ldsB[(wn * 64 + t * 16 + r16) * 32 + quad * 8];
        }
#pragma unroll
        for (int tm = 0; tm < 4; ++tm)
#pragma unroll
            for (int tn = 0; tn < 4; ++tn)
                acc[tm][tn] = __builtin_amdgcn_mfma_f32_16x16x32_bf16(
                    af[tm], bfr[tn], acc[tm][tn], 0, 0, 0);
    }

    // exp in place
#pragma unroll
    for (int tm = 0; tm < 4; ++tm)
#pragma unroll
        for (int tn = 0; tn < 4; ++tn)
#pragma unroll
            for (int r = 0; r < 4; ++r)
                acc[tm][tn][r] = __expf(acc[tm][tn][r] * TAU_INV);

    // rowsum: sum over the 128 cols in this tile, per row
#pragma unroll
    for (int tm = 0; tm < 4; ++tm) {
#pragma unroll
        for (int r = 0; r < 4; ++r) {
            float rs = 0.f;
#pragma unroll
            for (int tn = 0; tn < 4; ++tn) rs += acc[tm][tn][r];
#pragma unroll
            for (int m = 1; m < 16; m <<= 1) rs += __shfl_xor(rs, m, 64);
            if (r16 == 0)
                atomicAdd(&rowsum[bM + wm * 64 + tm * 16 + quad * 4 + r], rs);
        }
    }
    // colsum: sum over the 128 rows in this tile, per col
#pragma unroll
    for (int tn = 0; tn < 4; ++tn) {
        float cs = 0.f;
#pragma unroll
        for (int tm = 0; tm < 4; ++tm)
#pragma unroll
            for (int r = 0; r < 4; ++r) cs += acc[tm][tn][r];
        cs += __shfl_xor(cs, 16, 64);
        cs += __shfl_xor(cs, 32, 64);
        if (quad == 0)
            atomicAdd(&colsum[bN + wn * 64 + tn * 16 + r16], cs);
    }
}

// One wave per row: n = p/||p||, bf16 in place.
__global__ void normalize_rows(short* __restrict__ P, int nrows)
{
    int gt = blockIdx.x * blockDim.x + threadIdx.x;
    int row = gt >> 6, lane = gt & 63;
    if (row >= nrows) return;
    short* p = P + (size_t)row * HID + lane * 8;
    s16x8 v = *(const s16x8*)p;
    float f[8], ss = 0.f;
#pragma unroll
    for (int i = 0; i < 8; ++i) { f[i] = bf2f(v[i]); ss += f[i] * f[i]; }
#pragma unroll
    for (int m = 1; m < 64; m <<= 1) ss += __shfl_xor(ss, m, 64);
    float inv = rsqrtf(ss);
    s16x8 o;
#pragma unroll
    for (int i = 0; i < 8; ++i) o[i] = f2bf(f[i] * inv);
    *(s16x8*)p = o;
}

// 16 lanes per edge: smp[r] += exp(dot(n1[r],n2[c])/tau), ssc[r] += exp(dot(n1[c],n2[r])/tau)
__global__ void edge_kernel(const short* __restrict__ N1, const short* __restrict__ N2,
                            const int* __restrict__ pos, float* __restrict__ smp,
                            float* __restrict__ ssc, int E)
{
    int t = blockIdx.x * blockDim.x + threadIdx.x;
    int e = t >> 4, j = t & 15;
    if (e >= E) return;
    int r = pos[e], c = pos[E + e];
    const short* a1 = N1 + (size_t)r * HID + j * 32;
    const short* b1 = N2 + (size_t)c * HID + j * 32;
    const short* a2 = N1 + (size_t)c * HID + j * 32;
    const short* b2 = N2 + (size_t)r * HID + j * 32;
    float d1 = 0.f, d2 = 0.f;
#pragma unroll
    for (int u = 0; u < 4; ++u) {
        s16x8 x1 = *(const s16x8*)(a1 + u * 8);
        s16x8 y1 = *(const s16x8*)(b1 + u * 8);
        s16x8 x2 = *(const s16x8*)(a2 + u * 8);
        s16x8 y2 = *(const s16x8*)(b2 + u * 8);
#pragma unroll
        for (int i = 0; i < 8; ++i) {
            d1 = fmaf(bf2f(x1[i]), bf2f(y1[i]), d1);
            d2 = fmaf(bf2f(x2[i]), bf2f(y2[i]), d2);
        }
    }
#pragma unroll
    for (int m = 1; m < 16; m <<= 1) {
        d1 += __shfl_xor(d1, m, 64);
        d2 += __shfl_xor(d2, m, 64);
    }
    if (j == 0) {
        atomicAdd(&smp[r], __expf(d1 * TAU_INV));
        atomicAdd(&ssc[r], __expf(d2 * TAU_INV));
    }
}

__global__ void finalize(const float* __restrict__ rowsum, const float* __restrict__ colsum,
                         const float* __restrict__ smp, const float* __restrict__ ssc,
                         float* __restrict__ accum, int n)
{
    int i = blockIdx.x * blockDim.x + threadIdx.x;
    float contrib = 0.f;
    if (i < n) {
        float s1 = smp[i] / rowsum[i];
        float s2 = ssc[i] / colsum[i];
        contrib = -0.5f * (logf(s1) + logf(s2)) / (float)n;
    }
#pragma unroll
    for (int m = 1; m < 64; m <<= 1) contrib += __shfl_xor(contrib, m, 64);
    __shared__ float wsum[4];
    int w = threadIdx.x >> 6, lane = threadIdx.x & 63;
    if (lane == 0) wsum[w] = contrib;
    __syncthreads();
    if (threadIdx.x == 0)
        atomicAdd(accum, wsum[0] + wsum[1] + wsum[2] + wsum[3]);
}

__global__ void writeout(const float* __restrict__ accum, float* __restrict__ out)
{
    if (threadIdx.x == 0) out[0] = accum[0];
}

extern "C" void kernel_launch(void* const* d_in, const int* in_sizes, int n_in,
                              void* d_out, int out_size, void* d_ws, size_t ws_size,
                              hipStream_t stream)
{
    const float* z_mp = (const float*)d_in[0];
    const float* z_sc = (const float*)d_in[1];
    const float* W1f  = (const float*)d_in[2];
    const float* b1   = (const float*)d_in[3];
    const float* W2f  = (const float*)d_in[4];
    const float* b2   = (const float*)d_in[5];
    const int*   pos  = (const int*)d_in[6];
    const int E = in_sizes[6] / 2;
    const int ZN = NROWS * HID;       // 4M elems
    const int WN = HID * HID;         // 256K elems

    // workspace layout (~34 MB):
    //   [0,16MB)   : Zb_mp, Zb_sc (bf16) -> dead after proj1 -> reused as P1,P2
    //   [16,32MB)  : H1,H2 (bf16)
    //   [32MB,..)  : Wb1 (512K), Wb2 (512K), rowsum/colsum/smp/ssc (4x32KB), accum
    char* ws = (char*)d_ws;
    short* Zb1 = (short*)ws;
    short* Zb2 = Zb1 + ZN;
    short* P1  = Zb1;                 // alias: Zb dead after proj1
    short* P2  = Zb2;
    short* H1  = (short*)(ws + (size_t)16 * 1024 * 1024);
    short* H2  = H1 + ZN;
    short* Wb1 = (short*)(ws + (size_t)32 * 1024 * 1024);
    short* Wb2 = Wb1 + WN;
    float* rowsum = (float*)(Wb2 + WN);
    float* colsum = rowsum + NROWS;
    float* smp    = colsum + NROWS;
    float* ssc    = smp + NROWS;
    float* accum  = ssc + NROWS;

    dim3 blk(256);
    // fp32 -> bf16 conversions
    convert_f32_bf16<<<dim3(ZN / 4 / 256), blk, 0, stream>>>(z_mp, Zb1, ZN);
    convert_f32_bf16<<<dim3(ZN / 4 / 256), blk, 0, stream>>>(z_sc, Zb2, ZN);
    convert_f32_bf16<<<dim3(WN / 4 / 256), blk, 0, stream>>>(W1f, Wb1, WN);
    convert_f32_bf16<<<dim3(WN / 4 / 256), blk, 0, stream>>>(W2f, Wb2, WN);
    // zero accumulators
    hipMemsetAsync(rowsum, 0, (4 * NROWS + 1) * sizeof(float), stream);
    // H = elu(Z @ W1^T + b1) for both inputs (grid.z)
    gemm_proj<<<dim3(64, 4, 2), blk, 0, stream>>>(Zb1, Zb2, Wb1, b1, H1, H2, 1);
    // P = H @ W2^T + b2   (P overwrites Zb region — Zb dead now)
    gemm_proj<<<dim3(64, 4, 2), blk, 0, stream>>>(H1, H2, Wb2, b2, P1, P2, 0);
    // normalize P1,P2 (contiguous 2*NROWS rows) in place -> N1,N2
    normalize_rows<<<dim3((2 * NROWS) / 4), blk, 0, stream>>>(P1, 2 * NROWS);
    // rowsum/colsum of exp-cosine similarity (S never materialized)
    gemm_sim<<<dim3(64, 64), blk, 0, stream>>>(P1, P2, rowsum, colsum);
    // per-edge numerators, segment-summed by row via atomics
    edge_kernel<<<dim3((E * 16 + 255) / 256), blk, 0, stream>>>(P1, P2, pos, smp, ssc, E);
    finalize<<<dim3(NROWS / 256), blk, 0, stream>>>(rowsum, colsum, smp, ssc, accum, NROWS);
    writeout<<<dim3(1), dim3(64), 0, stream>>>(accum, (float*)d_out);
}